// Round 1
// baseline (380.258 us; speedup 1.0000x reference)
//
#include <hip/hip_runtime.h>

#define B_   16
#define P_   196
#define L_   80
#define DIM1 2048
#define DIM2 300
#define ATT  512

// ---------------- w_eff[a] = sum_c Wt[c] * Wh[c,a] ----------------
__global__ __launch_bounds__(512)
void weff_kernel(const float* __restrict__ Wh, const float* __restrict__ Wt,
                 float* __restrict__ w_eff) {
    const int a = threadIdx.x;  // 512 threads, 1 block
    float s = 0.f;
    for (int c = 0; c < ATT; ++c) s = fmaf(Wt[c], Wh[(size_t)c * ATT + a], s);
    w_eff[a] = s;
}

// ---------- generic tiled NT GEMM: C[M,N] = A[M,K] * B[N,K]^T ----------
// 64x64 tile, 256 threads, 4x4 per thread, BK=16. M,N must be multiples of 64.
__global__ __launch_bounds__(256)
void gemm_nt(const float* __restrict__ A, const float* __restrict__ Bm,
             float* __restrict__ C, int M, int N, int K) {
    constexpr int BK = 16;
    __shared__ float As[BK][64];
    __shared__ float Bs[BK][64];
    const int tid  = threadIdx.x;
    const int bm   = blockIdx.x * 64;
    const int bn   = blockIdx.y * 64;
    const int ty   = tid >> 4;        // 0..15 -> row quad
    const int tx   = tid & 15;        // 0..15 -> col quad
    const int lrow = tid >> 2;        // 0..63 loader row
    const int lc4  = (tid & 3) << 2;  // 0,4,8,12 loader k-offset
    float acc[4][4] = {};
    const float* Arow = A  + (size_t)(bm + lrow) * K;
    const float* Brow = Bm + (size_t)(bn + lrow) * K;

    for (int k0 = 0; k0 < K; k0 += BK) {
        float4 av, bv;
        if (k0 + BK <= K) {
            av = *(const float4*)(Arow + k0 + lc4);
            bv = *(const float4*)(Brow + k0 + lc4);
        } else {
            float a_[4], b_[4];
            #pragma unroll
            for (int i = 0; i < 4; ++i) {
                const int k = k0 + lc4 + i;
                a_[i] = (k < K) ? Arow[k] : 0.f;
                b_[i] = (k < K) ? Brow[k] : 0.f;
            }
            av = make_float4(a_[0], a_[1], a_[2], a_[3]);
            bv = make_float4(b_[0], b_[1], b_[2], b_[3]);
        }
        __syncthreads();   // previous iter's LDS reads done
        As[lc4 + 0][lrow] = av.x;
        As[lc4 + 1][lrow] = av.y;
        As[lc4 + 2][lrow] = av.z;
        As[lc4 + 3][lrow] = av.w;
        Bs[lc4 + 0][lrow] = bv.x;
        Bs[lc4 + 1][lrow] = bv.y;
        Bs[lc4 + 2][lrow] = bv.z;
        Bs[lc4 + 3][lrow] = bv.w;
        __syncthreads();
        #pragma unroll
        for (int k = 0; k < BK; ++k) {
            const float4 a4 = *(const float4*)&As[k][ty << 2];
            const float4 b4 = *(const float4*)&Bs[k][tx << 2];
            const float ae[4] = {a4.x, a4.y, a4.z, a4.w};
            const float be[4] = {b4.x, b4.y, b4.z, b4.w};
            #pragma unroll
            for (int i = 0; i < 4; ++i)
                #pragma unroll
                for (int j = 0; j < 4; ++j)
                    acc[i][j] = fmaf(ae[i], be[j], acc[i][j]);
        }
    }
    #pragma unroll
    for (int i = 0; i < 4; ++i) {
        float4 o = make_float4(acc[i][0], acc[i][1], acc[i][2], acc[i][3]);
        *(float4*)(C + (size_t)(bm + (ty << 2) + i) * N + bn + (tx << 2)) = o;
    }
}

// ------- fused score + softmax: one block per (b,l); writes alpha -------
__global__ __launch_bounds__(256)
void score_softmax_kernel(const float* __restrict__ p1, const float* __restrict__ p2,
                          const float* __restrict__ w_eff, float* __restrict__ alpha) {
    const int bl = blockIdx.x;     // b*L + l
    const int b  = bl / L_;
    __shared__ float s_p2[ATT];
    __shared__ float s_w[ATT];
    __shared__ float s_t[P_];
    __shared__ float s_red[4];
    const int tid = threadIdx.x;
    for (int i = tid; i < ATT; i += 256) {
        s_p2[i] = p2[(size_t)bl * ATT + i];
        s_w[i]  = w_eff[i];
    }
    __syncthreads();
    const int wave = tid >> 6, lane = tid & 63;
    const float4* sp2 = (const float4*)s_p2;
    const float4* sw  = (const float4*)s_w;
    for (int p = wave; p < P_; p += 4) {
        const float4* row = (const float4*)(p1 + ((size_t)b * P_ + p) * ATT);
        float acc = 0.f;
        #pragma unroll
        for (int it = 0; it < ATT / 256; ++it) {   // 2 iters of float4
            const int a4 = it * 64 + lane;
            const float4 r = row[a4];
            const float4 q = sp2[a4];
            const float4 w = sw[a4];
            const float xs[4] = {r.x * q.x, r.y * q.y, r.z * q.z, r.w * q.w};
            const float ws[4] = {w.x, w.y, w.z, w.w};
            #pragma unroll
            for (int j = 0; j < 4; ++j) {
                const float e  = __expf(2.f * xs[j]);
                const float th = 1.f - 2.f / (e + 1.f);   // tanh(x)
                acc = fmaf(th, ws[j], acc);
            }
        }
        #pragma unroll
        for (int off = 32; off >= 1; off >>= 1) acc += __shfl_xor(acc, off);
        if (lane == 0) s_t[p] = acc;
    }
    __syncthreads();
    // softmax over the 196 scores (bias term cancels; TAU = 1)
    const float v = (tid < P_) ? s_t[tid] : -1e30f;
    float m = v;
    #pragma unroll
    for (int off = 32; off >= 1; off >>= 1) m = fmaxf(m, __shfl_xor(m, off));
    if (lane == 0) s_red[wave] = m;
    __syncthreads();
    m = fmaxf(fmaxf(s_red[0], s_red[1]), fmaxf(s_red[2], s_red[3]));
    __syncthreads();   // everyone has read the maxes before s_red reuse
    const float e = (tid < P_) ? __expf(v - m) : 0.f;
    float s = e;
    #pragma unroll
    for (int off = 32; off >= 1; off >>= 1) s += __shfl_xor(s, off);
    if (lane == 0) s_red[wave] = s;
    __syncthreads();
    s = s_red[0] + s_red[1] + s_red[2] + s_red[3];
    if (tid < P_) alpha[(size_t)bl * P_ + tid] = e / s;
}

// ------- label_repr[b,l,d] = sum_p alpha[b,l,p] * x1[b,p,d] -------
// grid: (B, L/16, DIM1/256); 16 l's per block in registers.
__global__ __launch_bounds__(256)
void label_kernel(const float* __restrict__ alpha, const float* __restrict__ x1,
                  float* __restrict__ out) {
    const int b  = blockIdx.x;
    const int lt = blockIdx.y;
    const int dt = blockIdx.z;
    __shared__ float s_alpha[16][P_];
    const int tid = threadIdx.x;
    for (int idx = tid; idx < 16 * P_; idx += 256) {
        const int i = idx / P_, p = idx - i * P_;
        s_alpha[i][p] = alpha[(size_t)(b * L_ + lt * 16 + i) * P_ + p];
    }
    __syncthreads();
    const int d = dt * 256 + tid;
    const float* xcol = x1 + (size_t)b * P_ * DIM1 + d;
    float acc[16] = {};
    #pragma unroll 4
    for (int p = 0; p < P_; ++p) {
        const float xv = xcol[(size_t)p * DIM1];
        #pragma unroll
        for (int i = 0; i < 16; ++i) acc[i] = fmaf(s_alpha[i][p], xv, acc[i]);
    }
    #pragma unroll
    for (int i = 0; i < 16; ++i)
        out[(size_t)(b * L_ + lt * 16 + i) * DIM1 + d] = acc[i];
}

extern "C" void kernel_launch(void* const* d_in, const int* in_sizes, int n_in,
                              void* d_out, int out_size, void* d_ws, size_t ws_size,
                              hipStream_t stream) {
    const float* x1 = (const float*)d_in[0];   // (B,P,DIM1)
    const float* x2 = (const float*)d_in[1];   // (B,L,DIM2)
    const float* W1 = (const float*)d_in[2];   // (ATT,DIM1)
    const float* W2 = (const float*)d_in[3];   // (ATT,DIM2)
    const float* Wh = (const float*)d_in[4];   // (ATT,ATT)
    const float* Wt = (const float*)d_in[6];   // (1,ATT)
    // bh (d_in[5]) and bt (d_in[7]) cancel in the softmax — unused.

    float* ws    = (float*)d_ws;
    float* p1    = ws;                                  // 3136*512
    float* p2    = p1 + (size_t)B_ * P_ * ATT;          // 1280*512
    float* w_eff = p2 + (size_t)B_ * L_ * ATT;          // 512

    float* label = (float*)d_out;                        // (B,L,DIM1)
    float* alpha = label + (size_t)B_ * L_ * DIM1;       // (B,L,P)

    hipLaunchKernelGGL(weff_kernel, dim3(1), dim3(512), 0, stream, Wh, Wt, w_eff);
    hipLaunchKernelGGL(gemm_nt, dim3((B_ * L_) / 64, ATT / 64), dim3(256), 0, stream,
                       x2, W2, p2, B_ * L_, ATT, DIM2);
    hipLaunchKernelGGL(gemm_nt, dim3((B_ * P_) / 64, ATT / 64), dim3(256), 0, stream,
                       x1, W1, p1, B_ * P_, ATT, DIM1);
    hipLaunchKernelGGL(score_softmax_kernel, dim3(B_ * L_), dim3(256), 0, stream,
                       p1, p2, w_eff, alpha);
    hipLaunchKernelGGL(label_kernel, dim3(B_, L_ / 16, DIM1 / 256), dim3(256), 0, stream,
                       alpha, x1, label);
}

// Round 2
// 261.879 us; speedup vs baseline: 1.4520x; 1.4520x over previous
//
#include <hip/hip_runtime.h>

#define B_   16
#define P_   196
#define L_   80
#define DIM1 2048
#define DIM2 300
#define ATT  512

typedef __attribute__((ext_vector_type(8))) short short8x;
typedef __attribute__((ext_vector_type(4))) float f32x4;
typedef __attribute__((ext_vector_type(4))) unsigned int uint4x;
typedef __attribute__((ext_vector_type(4))) unsigned short ushort4x;

// ---------------- w_eff[a] = sum_c Wt[c] * Wh[c,a] ----------------
__global__ __launch_bounds__(512)
void weff_kernel(const float* __restrict__ Wh, const float* __restrict__ Wt,
                 float* __restrict__ w_eff) {
    const int a = threadIdx.x;  // 512 threads, 1 block
    float s = 0.f;
    for (int c = 0; c < ATT; ++c) s = fmaf(Wt[c], Wh[(size_t)c * ATT + a], s);
    w_eff[a] = s;
}

// ---------------- fp32 -> bf16 (RN-even), vectorized x4 ----------------
__global__ __launch_bounds__(256)
void cvt_bf16_kernel(const float* __restrict__ in, unsigned short* __restrict__ out, int n4) {
    for (int i = blockIdx.x * 256 + threadIdx.x; i < n4; i += gridDim.x * 256) {
        uint4x u = ((const uint4x*)in)[i];
        ushort4x o;
        #pragma unroll
        for (int j = 0; j < 4; ++j) {
            unsigned v = u[j];
            v += 0x7fffu + ((v >> 16) & 1u);
            o[j] = (unsigned short)(v >> 16);
        }
        ((ushort4x*)out)[i] = o;
    }
}

// ---------------- bf16 MFMA GEMM: C[M,N] = A[M,K] * B[N,K]^T ----------------
// M=3136, N=512, K=2048. 64x64 tile, BK=64, 4 waves (2x2 of 32x32 quadrants),
// double-buffered LDS via global_load_lds(16B) with both-sides XOR swizzle.
#define GM 3136
#define GN 512
#define GK 2048

__device__ __forceinline__ void gload16(const unsigned short* g, unsigned short* l) {
    __builtin_amdgcn_global_load_lds(
        (const __attribute__((address_space(1))) unsigned int*)g,
        (__attribute__((address_space(3))) unsigned int*)l, 16, 0, 0);
}

__global__ __launch_bounds__(256)
void gemm_bf16_mfma(const unsigned short* __restrict__ Ab,
                    const unsigned short* __restrict__ Bb,
                    float* __restrict__ C) {
    __shared__ unsigned short As[2][64 * 64];
    __shared__ unsigned short Bs[2][64 * 64];
    const int tid  = threadIdx.x;
    const int wid  = tid >> 6;
    const int lane = tid & 63;
    const int bm   = blockIdx.x * 64;
    const int bn   = blockIdx.y * 64;
    const int wm   = wid >> 1;          // 0,1
    const int wn   = wid & 1;           // 0,1

    // staging geometry: per issue a wave covers 8 rows x 64 cols (16B/lane).
    // source column pre-swizzled so that (linear LDS dest) == swizzled layout.
    const int srow = lane >> 3;                       // 0..7 row within group (== r&7)
    const int scol = ((lane & 7) ^ srow) << 3;        // swizzled col element
    const size_t arow0 = (size_t)(bm + (wid << 4) + srow) * GK;
    const size_t brow0 = (size_t)(bn + (wid << 4) + srow) * GK;

#define STAGE_TILE(buf, k0)                                                        \
    {                                                                              \
        gload16(Ab + arow0 + (k0) + scol,            &As[buf][((wid << 4) + 0) * 64]); \
        gload16(Ab + arow0 + (size_t)8 * GK + (k0) + scol, &As[buf][((wid << 4) + 8) * 64]); \
        gload16(Bb + brow0 + (k0) + scol,            &Bs[buf][((wid << 4) + 0) * 64]); \
        gload16(Bb + brow0 + (size_t)8 * GK + (k0) + scol, &Bs[buf][((wid << 4) + 8) * 64]); \
    }

    f32x4 acc[2][2] = {};
    const int fr  = lane & 15;            // fragment row/col within 16
    const int kb  = (lane >> 4) << 3;     // k offset 0,8,16,24
    const int swz = (lane & 7) << 4;      // read-side XOR (r&7)<<4, r&7 == lane&7

    STAGE_TILE(0, 0)
    constexpr int NT = GK / 64;
    for (int kt = 0; kt < NT; ++kt) {
        __syncthreads();                          // staged tile kt visible (vmcnt drained)
        if (kt + 1 < NT) STAGE_TILE((kt + 1) & 1, (kt + 1) * 64)
        const char* pa = (const char*)&As[kt & 1][0];
        const char* pb = (const char*)&Bs[kt & 1][0];
        #pragma unroll
        for (int kk = 0; kk < 2; ++kk) {
            const int koff = ((kk * 32 + kb) * 2) ^ swz;
            short8x a[2], b[2];
            #pragma unroll
            for (int m = 0; m < 2; ++m)
                a[m] = *(const short8x*)(pa + (wm * 32 + m * 16 + fr) * 128 + koff);
            #pragma unroll
            for (int n = 0; n < 2; ++n)
                b[n] = *(const short8x*)(pb + (wn * 32 + n * 16 + fr) * 128 + koff);
            #pragma unroll
            for (int m = 0; m < 2; ++m)
                #pragma unroll
                for (int n = 0; n < 2; ++n)
                    acc[m][n] = __builtin_amdgcn_mfma_f32_16x16x32_bf16(a[m], b[n], acc[m][n], 0, 0, 0);
        }
        __syncthreads();                          // all reads of buf done before next overwrite
    }

    const int crow = (lane >> 4) << 2;
    #pragma unroll
    for (int m = 0; m < 2; ++m)
        #pragma unroll
        for (int n = 0; n < 2; ++n)
            #pragma unroll
            for (int j = 0; j < 4; ++j)
                C[(size_t)(bm + wm * 32 + m * 16 + crow + j) * GN + bn + wn * 32 + n * 16 + fr] =
                    acc[m][n][j];
#undef STAGE_TILE
}

// ---------- generic tiled NT GEMM (fp32): C[M,N] = A[M,K] * B[N,K]^T ----------
__global__ __launch_bounds__(256)
void gemm_nt(const float* __restrict__ A, const float* __restrict__ Bm,
             float* __restrict__ C, int M, int N, int K) {
    constexpr int BK = 16;
    __shared__ float As[BK][64];
    __shared__ float Bs[BK][64];
    const int tid  = threadIdx.x;
    const int bm   = blockIdx.x * 64;
    const int bn   = blockIdx.y * 64;
    const int ty   = tid >> 4;
    const int tx   = tid & 15;
    const int lrow = tid >> 2;
    const int lc4  = (tid & 3) << 2;
    float acc[4][4] = {};
    const float* Arow = A  + (size_t)(bm + lrow) * K;
    const float* Brow = Bm + (size_t)(bn + lrow) * K;

    for (int k0 = 0; k0 < K; k0 += BK) {
        float4 av, bv;
        if (k0 + BK <= K) {
            av = *(const float4*)(Arow + k0 + lc4);
            bv = *(const float4*)(Brow + k0 + lc4);
        } else {
            float a_[4], b_[4];
            #pragma unroll
            for (int i = 0; i < 4; ++i) {
                const int k = k0 + lc4 + i;
                a_[i] = (k < K) ? Arow[k] : 0.f;
                b_[i] = (k < K) ? Brow[k] : 0.f;
            }
            av = make_float4(a_[0], a_[1], a_[2], a_[3]);
            bv = make_float4(b_[0], b_[1], b_[2], b_[3]);
        }
        __syncthreads();
        As[lc4 + 0][lrow] = av.x;
        As[lc4 + 1][lrow] = av.y;
        As[lc4 + 2][lrow] = av.z;
        As[lc4 + 3][lrow] = av.w;
        Bs[lc4 + 0][lrow] = bv.x;
        Bs[lc4 + 1][lrow] = bv.y;
        Bs[lc4 + 2][lrow] = bv.z;
        Bs[lc4 + 3][lrow] = bv.w;
        __syncthreads();
        #pragma unroll
        for (int k = 0; k < BK; ++k) {
            const float4 a4 = *(const float4*)&As[k][ty << 2];
            const float4 b4 = *(const float4*)&Bs[k][tx << 2];
            const float ae[4] = {a4.x, a4.y, a4.z, a4.w};
            const float be[4] = {b4.x, b4.y, b4.z, b4.w};
            #pragma unroll
            for (int i = 0; i < 4; ++i)
                #pragma unroll
                for (int j = 0; j < 4; ++j)
                    acc[i][j] = fmaf(ae[i], be[j], acc[i][j]);
        }
    }
    #pragma unroll
    for (int i = 0; i < 4; ++i) {
        float4 o = make_float4(acc[i][0], acc[i][1], acc[i][2], acc[i][3]);
        *(float4*)(C + (size_t)(bm + (ty << 2) + i) * N + bn + (tx << 2)) = o;
    }
}

// ------- fused score + softmax: one block per (b,l); writes alpha -------
__global__ __launch_bounds__(256)
void score_softmax_kernel(const float* __restrict__ p1, const float* __restrict__ p2,
                          const float* __restrict__ w_eff, float* __restrict__ alpha) {
    const int bl = blockIdx.x;     // b*L + l
    const int b  = bl / L_;
    __shared__ float s_p2[ATT];
    __shared__ float s_w[ATT];
    __shared__ float s_t[P_];
    __shared__ float s_red[4];
    const int tid = threadIdx.x;
    for (int i = tid; i < ATT; i += 256) {
        s_p2[i] = p2[(size_t)bl * ATT + i];
        s_w[i]  = w_eff[i];
    }
    __syncthreads();
    const int wave = tid >> 6, lane = tid & 63;
    const float4* sp2 = (const float4*)s_p2;
    const float4* sw  = (const float4*)s_w;
    for (int p = wave; p < P_; p += 4) {
        const float4* row = (const float4*)(p1 + ((size_t)b * P_ + p) * ATT);
        float acc = 0.f;
        #pragma unroll
        for (int it = 0; it < ATT / 256; ++it) {   // 2 iters of float4
            const int a4 = it * 64 + lane;
            const float4 r = row[a4];
            const float4 q = sp2[a4];
            const float4 w = sw[a4];
            const float xs[4] = {r.x * q.x, r.y * q.y, r.z * q.z, r.w * q.w};
            const float ws[4] = {w.x, w.y, w.z, w.w};
            #pragma unroll
            for (int j = 0; j < 4; ++j) {
                const float e  = __expf(2.f * xs[j]);
                const float th = 1.f - 2.f / (e + 1.f);   // tanh(x)
                acc = fmaf(th, ws[j], acc);
            }
        }
        #pragma unroll
        for (int off = 32; off >= 1; off >>= 1) acc += __shfl_xor(acc, off);
        if (lane == 0) s_t[p] = acc;
    }
    __syncthreads();
    // softmax over the 196 scores (bias term cancels; TAU = 1)
    const float v = (tid < P_) ? s_t[tid] : -1e30f;
    float m = v;
    #pragma unroll
    for (int off = 32; off >= 1; off >>= 1) m = fmaxf(m, __shfl_xor(m, off));
    if (lane == 0) s_red[wave] = m;
    __syncthreads();
    m = fmaxf(fmaxf(s_red[0], s_red[1]), fmaxf(s_red[2], s_red[3]));
    __syncthreads();
    const float e = (tid < P_) ? __expf(v - m) : 0.f;
    float s = e;
    #pragma unroll
    for (int off = 32; off >= 1; off >>= 1) s += __shfl_xor(s, off);
    if (lane == 0) s_red[wave] = s;
    __syncthreads();
    s = s_red[0] + s_red[1] + s_red[2] + s_red[3];
    if (tid < P_) alpha[(size_t)bl * P_ + tid] = e / s;
}

// ------- label_repr[b,l,d] = sum_p alpha[b,l,p] * x1[b,p,d] -------
__global__ __launch_bounds__(256)
void label_kernel(const float* __restrict__ alpha, const float* __restrict__ x1,
                  float* __restrict__ out) {
    const int b  = blockIdx.x;
    const int lt = blockIdx.y;
    const int dt = blockIdx.z;
    __shared__ float s_alpha[16][P_];
    const int tid = threadIdx.x;
    for (int idx = tid; idx < 16 * P_; idx += 256) {
        const int i = idx / P_, p = idx - i * P_;
        s_alpha[i][p] = alpha[(size_t)(b * L_ + lt * 16 + i) * P_ + p];
    }
    __syncthreads();
    const int d = dt * 256 + tid;
    const float* xcol = x1 + (size_t)b * P_ * DIM1 + d;
    float acc[16] = {};
    #pragma unroll 4
    for (int p = 0; p < P_; ++p) {
        const float xv = xcol[(size_t)p * DIM1];
        #pragma unroll
        for (int i = 0; i < 16; ++i) acc[i] = fmaf(s_alpha[i][p], xv, acc[i]);
    }
    #pragma unroll
    for (int i = 0; i < 16; ++i)
        out[(size_t)(b * L_ + lt * 16 + i) * DIM1 + d] = acc[i];
}

extern "C" void kernel_launch(void* const* d_in, const int* in_sizes, int n_in,
                              void* d_out, int out_size, void* d_ws, size_t ws_size,
                              hipStream_t stream) {
    const float* x1 = (const float*)d_in[0];   // (B,P,DIM1)
    const float* x2 = (const float*)d_in[1];   // (B,L,DIM2)
    const float* W1 = (const float*)d_in[2];   // (ATT,DIM1)
    const float* W2 = (const float*)d_in[3];   // (ATT,DIM2)
    const float* Wh = (const float*)d_in[4];   // (ATT,ATT)
    const float* Wt = (const float*)d_in[6];   // (1,ATT)
    // bh (d_in[5]) and bt (d_in[7]) cancel in the softmax — unused.

    float* ws    = (float*)d_ws;
    float* p1    = ws;                                   // 3136*512 f32
    float* p2    = p1 + (size_t)B_ * P_ * ATT;           // 1280*512 f32
    float* w_eff = p2 + (size_t)B_ * L_ * ATT;           // 512 f32
    unsigned short* x1b = (unsigned short*)(w_eff + ATT);        // 3136*2048 bf16
    unsigned short* W1b = x1b + (size_t)B_ * P_ * DIM1;          // 512*2048 bf16

    float* label = (float*)d_out;                        // (B,L,DIM1)
    float* alpha = label + (size_t)B_ * L_ * DIM1;       // (B,L,P)

    hipLaunchKernelGGL(cvt_bf16_kernel, dim3(2048), dim3(256), 0, stream,
                       x1, x1b, (B_ * P_ * DIM1) / 4);
    hipLaunchKernelGGL(cvt_bf16_kernel, dim3(512), dim3(256), 0, stream,
                       W1, W1b, (ATT * DIM1) / 4);
    hipLaunchKernelGGL(weff_kernel, dim3(1), dim3(512), 0, stream, Wh, Wt, w_eff);
    hipLaunchKernelGGL(gemm_nt, dim3((B_ * L_) / 64, ATT / 64), dim3(256), 0, stream,
                       x2, W2, p2, B_ * L_, ATT, DIM2);
    hipLaunchKernelGGL(gemm_bf16_mfma, dim3(GM / 64, GN / 64), dim3(256), 0, stream,
                       x1b, W1b, p1);
    hipLaunchKernelGGL(score_softmax_kernel, dim3(B_ * L_), dim3(256), 0, stream,
                       p1, p2, w_eff, alpha);
    hipLaunchKernelGGL(label_kernel, dim3(B_, L_ / 16, DIM1 / 256), dim3(256), 0, stream,
                       alpha, x1, label);
}

// Round 3
// 257.199 us; speedup vs baseline: 1.4785x; 1.0182x over previous
//
#include <hip/hip_runtime.h>

#define B_   16
#define P_   196
#define L_   80
#define DIM1 2048
#define DIM2 300
#define ATT  512

typedef __attribute__((ext_vector_type(8))) short short8x;
typedef __attribute__((ext_vector_type(4))) float f32x4;
typedef __attribute__((ext_vector_type(4))) unsigned int uint4x;
typedef __attribute__((ext_vector_type(4))) unsigned short ushort4x;

// ---------------- w_eff[a] = sum_c Wt[c] * Wh[c,a] ----------------
// 8 blocks x 256 threads; block g covers a in [64g, 64g+64), 4 waves split c.
__global__ __launch_bounds__(256)
void weff_kernel(const float* __restrict__ Wh, const float* __restrict__ Wt,
                 float* __restrict__ w_eff) {
    __shared__ float part[4][64];
    const int tid = threadIdx.x, lane = tid & 63, quad = tid >> 6;
    const int a = blockIdx.x * 64 + lane;
    float s = 0.f;
    const int c0 = quad * 128;
    for (int c = c0; c < c0 + 128; ++c)
        s = fmaf(Wt[c], Wh[(size_t)c * ATT + a], s);
    part[quad][lane] = s;
    __syncthreads();
    if (tid < 64)
        w_eff[blockIdx.x * 64 + tid] =
            (part[0][tid] + part[1][tid]) + (part[2][tid] + part[3][tid]);
}

// ---------------- fp32 -> bf16 (RN-even), vectorized x4 ----------------
__global__ __launch_bounds__(256)
void cvt_bf16_kernel(const float* __restrict__ in, unsigned short* __restrict__ out, int n4) {
    for (int i = blockIdx.x * 256 + threadIdx.x; i < n4; i += gridDim.x * 256) {
        uint4x u = ((const uint4x*)in)[i];
        ushort4x o;
        #pragma unroll
        for (int j = 0; j < 4; ++j) {
            unsigned v = u[j];
            v += 0x7fffu + ((v >> 16) & 1u);
            o[j] = (unsigned short)(v >> 16);
        }
        ((ushort4x*)out)[i] = o;
    }
}

// ---------------- bf16 MFMA GEMM: C[M,N] = A[M,K] * B[N,K]^T ----------------
#define GM 3136
#define GN 512
#define GK 2048

__device__ __forceinline__ void gload16(const unsigned short* g, unsigned short* l) {
    __builtin_amdgcn_global_load_lds(
        (const __attribute__((address_space(1))) unsigned int*)g,
        (__attribute__((address_space(3))) unsigned int*)l, 16, 0, 0);
}

__global__ __launch_bounds__(256)
void gemm_bf16_mfma(const unsigned short* __restrict__ Ab,
                    const unsigned short* __restrict__ Bb,
                    float* __restrict__ C) {
    __shared__ unsigned short As[2][64 * 64];
    __shared__ unsigned short Bs[2][64 * 64];
    const int tid  = threadIdx.x;
    const int wid  = tid >> 6;
    const int lane = tid & 63;
    const int bm   = blockIdx.x * 64;
    const int bn   = blockIdx.y * 64;
    const int wm   = wid >> 1;          // 0,1
    const int wn   = wid & 1;           // 0,1

    const int srow = lane >> 3;                       // 0..7
    const int scol = ((lane & 7) ^ srow) << 3;        // pre-swizzled source col
    const size_t arow0 = (size_t)(bm + (wid << 4) + srow) * GK;
    const size_t brow0 = (size_t)(bn + (wid << 4) + srow) * GK;

#define STAGE_TILE(buf, k0)                                                        \
    {                                                                              \
        gload16(Ab + arow0 + (k0) + scol,            &As[buf][((wid << 4) + 0) * 64]); \
        gload16(Ab + arow0 + (size_t)8 * GK + (k0) + scol, &As[buf][((wid << 4) + 8) * 64]); \
        gload16(Bb + brow0 + (k0) + scol,            &Bs[buf][((wid << 4) + 0) * 64]); \
        gload16(Bb + brow0 + (size_t)8 * GK + (k0) + scol, &Bs[buf][((wid << 4) + 8) * 64]); \
    }

    f32x4 acc[2][2] = {};
    const int fr  = lane & 15;
    const int kb  = (lane >> 4) << 3;
    const int swz = (lane & 7) << 4;

    STAGE_TILE(0, 0)
    constexpr int NT = GK / 64;
    for (int kt = 0; kt < NT; ++kt) {
        __syncthreads();
        if (kt + 1 < NT) STAGE_TILE((kt + 1) & 1, (kt + 1) * 64)
        const char* pa = (const char*)&As[kt & 1][0];
        const char* pb = (const char*)&Bs[kt & 1][0];
        #pragma unroll
        for (int kk = 0; kk < 2; ++kk) {
            const int koff = ((kk * 32 + kb) * 2) ^ swz;
            short8x a[2], b[2];
            #pragma unroll
            for (int m = 0; m < 2; ++m)
                a[m] = *(const short8x*)(pa + (wm * 32 + m * 16 + fr) * 128 + koff);
            #pragma unroll
            for (int n = 0; n < 2; ++n)
                b[n] = *(const short8x*)(pb + (wn * 32 + n * 16 + fr) * 128 + koff);
            #pragma unroll
            for (int m = 0; m < 2; ++m)
                #pragma unroll
                for (int n = 0; n < 2; ++n)
                    acc[m][n] = __builtin_amdgcn_mfma_f32_16x16x32_bf16(a[m], b[n], acc[m][n], 0, 0, 0);
        }
        __syncthreads();
    }

    const int crow = (lane >> 4) << 2;
    #pragma unroll
    for (int m = 0; m < 2; ++m)
        #pragma unroll
        for (int n = 0; n < 2; ++n)
            #pragma unroll
            for (int j = 0; j < 4; ++j)
                C[(size_t)(bm + wm * 32 + m * 16 + crow + j) * GN + bn + wn * 32 + n * 16 + fr] =
                    acc[m][n][j];
#undef STAGE_TILE
}

// ---------- generic tiled NT GEMM (fp32): C[M,N] = A[M,K] * B[N,K]^T ----------
__global__ __launch_bounds__(256)
void gemm_nt(const float* __restrict__ A, const float* __restrict__ Bm,
             float* __restrict__ C, int M, int N, int K) {
    constexpr int BK = 16;
    __shared__ float As[BK][64];
    __shared__ float Bs[BK][64];
    const int tid  = threadIdx.x;
    const int bm   = blockIdx.x * 64;
    const int bn   = blockIdx.y * 64;
    const int ty   = tid >> 4;
    const int tx   = tid & 15;
    const int lrow = tid >> 2;
    const int lc4  = (tid & 3) << 2;
    float acc[4][4] = {};
    const float* Arow = A  + (size_t)(bm + lrow) * K;
    const float* Brow = Bm + (size_t)(bn + lrow) * K;

    for (int k0 = 0; k0 < K; k0 += BK) {
        float4 av, bv;
        if (k0 + BK <= K) {
            av = *(const float4*)(Arow + k0 + lc4);
            bv = *(const float4*)(Brow + k0 + lc4);
        } else {
            float a_[4], b_[4];
            #pragma unroll
            for (int i = 0; i < 4; ++i) {
                const int k = k0 + lc4 + i;
                a_[i] = (k < K) ? Arow[k] : 0.f;
                b_[i] = (k < K) ? Brow[k] : 0.f;
            }
            av = make_float4(a_[0], a_[1], a_[2], a_[3]);
            bv = make_float4(b_[0], b_[1], b_[2], b_[3]);
        }
        __syncthreads();
        As[lc4 + 0][lrow] = av.x;
        As[lc4 + 1][lrow] = av.y;
        As[lc4 + 2][lrow] = av.z;
        As[lc4 + 3][lrow] = av.w;
        Bs[lc4 + 0][lrow] = bv.x;
        Bs[lc4 + 1][lrow] = bv.y;
        Bs[lc4 + 2][lrow] = bv.z;
        Bs[lc4 + 3][lrow] = bv.w;
        __syncthreads();
        #pragma unroll
        for (int k = 0; k < BK; ++k) {
            const float4 a4 = *(const float4*)&As[k][ty << 2];
            const float4 b4 = *(const float4*)&Bs[k][tx << 2];
            const float ae[4] = {a4.x, a4.y, a4.z, a4.w};
            const float be[4] = {b4.x, b4.y, b4.z, b4.w};
            #pragma unroll
            for (int i = 0; i < 4; ++i)
                #pragma unroll
                for (int j = 0; j < 4; ++j)
                    acc[i][j] = fmaf(ae[i], be[j], acc[i][j]);
        }
    }
    #pragma unroll
    for (int i = 0; i < 4; ++i) {
        float4 o = make_float4(acc[i][0], acc[i][1], acc[i][2], acc[i][3]);
        *(float4*)(C + (size_t)(bm + (ty << 2) + i) * N + bn + (tx << 2)) = o;
    }
}

// ------- fused score + softmax: one block per (b,l); writes alpha -------
// score t = Wsum - 2*S with S = sum_a w_a * rcp(exp2(p1*p2*2log2e)+1); Wsum
// is constant over p so it cancels in softmax -> use v = -2*S directly.
#define LOG2E2 2.8853900817779268f   // 2*log2(e)

__global__ __launch_bounds__(256)
void score_softmax_kernel(const float* __restrict__ p1, const float* __restrict__ p2,
                          const float* __restrict__ w_eff, float* __restrict__ alpha) {
    // XCD-chunked swizzle: 1280 blocks = 8 XCDs x 160 -> same-b blocks share L2
    const int bidx = blockIdx.x;
    const int bl = (bidx & 7) * 160 + (bidx >> 3);
    const int b  = bl / L_;
    __shared__ float s_t[P_];
    __shared__ float s_red[4];
    const int tid = threadIdx.x, wave = tid >> 6, lane = tid & 63;

    // per-lane a-slots: float4 indices lane and 64+lane, fixed across rows
    const float4* gp2 = (const float4*)(p2 + (size_t)bl * ATT);
    const float4* gw  = (const float4*)w_eff;
    const float4 q0 = gp2[lane], q1 = gp2[64 + lane];
    const float4 w0 = gw[lane],  w1 = gw[64 + lane];
    float qa[8] = {q0.x * LOG2E2, q0.y * LOG2E2, q0.z * LOG2E2, q0.w * LOG2E2,
                   q1.x * LOG2E2, q1.y * LOG2E2, q1.z * LOG2E2, q1.w * LOG2E2};
    float wa[8] = {w0.x, w0.y, w0.z, w0.w, w1.x, w1.y, w1.z, w1.w};

    const float* p1b = p1 + (size_t)b * P_ * ATT;
    for (int p = wave; p < P_; p += 4) {
        const float4* row = (const float4*)(p1b + (size_t)p * ATT);
        const float4 r0 = row[lane], r1 = row[64 + lane];
        const float rr[8] = {r0.x, r0.y, r0.z, r0.w, r1.x, r1.y, r1.z, r1.w};
        float acc = 0.f;
        #pragma unroll
        for (int j = 0; j < 8; ++j) {
            const float e = __builtin_amdgcn_exp2f(rr[j] * qa[j]);
            acc = fmaf(wa[j], __builtin_amdgcn_rcpf(e + 1.f), acc);
        }
        #pragma unroll
        for (int off = 32; off >= 1; off >>= 1) acc += __shfl_xor(acc, off);
        if (lane == 0) s_t[p] = acc;
    }
    __syncthreads();
    // softmax over p of v = -2*S   (TAU = 1; bias & Wsum cancel)
    const float v = (tid < P_) ? -2.f * s_t[tid] : -1e30f;
    float m = v;
    #pragma unroll
    for (int off = 32; off >= 1; off >>= 1) m = fmaxf(m, __shfl_xor(m, off));
    if (lane == 0) s_red[wave] = m;
    __syncthreads();
    m = fmaxf(fmaxf(s_red[0], s_red[1]), fmaxf(s_red[2], s_red[3]));
    __syncthreads();
    const float e = (tid < P_) ? __expf(v - m) : 0.f;
    float s = e;
    #pragma unroll
    for (int off = 32; off >= 1; off >>= 1) s += __shfl_xor(s, off);
    if (lane == 0) s_red[wave] = s;
    __syncthreads();
    s = s_red[0] + s_red[1] + s_red[2] + s_red[3];
    if (tid < P_) alpha[(size_t)bl * P_ + tid] = e / s;
}

// ------- label_repr[b,l,d] = sum_p alpha[b,l,p] * x1[b,p,d] -------
// grid: (B, 2, DIM1/256); 40 l's per block in registers (x1 read only 2x).
__global__ __launch_bounds__(256)
void label_kernel(const float* __restrict__ alpha, const float* __restrict__ x1,
                  float* __restrict__ out) {
    const int b  = blockIdx.x;
    const int lt = blockIdx.y;
    const int dt = blockIdx.z;
    __shared__ float s_alpha[40][P_];
    const int tid = threadIdx.x;
    for (int idx = tid; idx < 40 * P_; idx += 256) {
        const int i = idx / P_, p = idx - i * P_;
        s_alpha[i][p] = alpha[(size_t)(b * L_ + lt * 40 + i) * P_ + p];
    }
    __syncthreads();
    const int d = dt * 256 + tid;
    const float* xcol = x1 + (size_t)b * P_ * DIM1 + d;
    float acc[40] = {};
    #pragma unroll 2
    for (int p = 0; p < P_; ++p) {
        const float xv = xcol[(size_t)p * DIM1];
        #pragma unroll
        for (int i = 0; i < 40; ++i) acc[i] = fmaf(s_alpha[i][p], xv, acc[i]);
    }
    #pragma unroll
    for (int i = 0; i < 40; ++i)
        out[(size_t)(b * L_ + lt * 40 + i) * DIM1 + d] = acc[i];
}

extern "C" void kernel_launch(void* const* d_in, const int* in_sizes, int n_in,
                              void* d_out, int out_size, void* d_ws, size_t ws_size,
                              hipStream_t stream) {
    const float* x1 = (const float*)d_in[0];   // (B,P,DIM1)
    const float* x2 = (const float*)d_in[1];   // (B,L,DIM2)
    const float* W1 = (const float*)d_in[2];   // (ATT,DIM1)
    const float* W2 = (const float*)d_in[3];   // (ATT,DIM2)
    const float* Wh = (const float*)d_in[4];   // (ATT,ATT)
    const float* Wt = (const float*)d_in[6];   // (1,ATT)
    // bh (d_in[5]) and bt (d_in[7]) cancel in the softmax — unused.

    float* ws    = (float*)d_ws;
    float* p1    = ws;                                   // 3136*512 f32
    float* p2    = p1 + (size_t)B_ * P_ * ATT;           // 1280*512 f32
    float* w_eff = p2 + (size_t)B_ * L_ * ATT;           // 512 f32
    unsigned short* x1b = (unsigned short*)(w_eff + ATT);        // 3136*2048 bf16
    unsigned short* W1b = x1b + (size_t)B_ * P_ * DIM1;          // 512*2048 bf16

    float* label = (float*)d_out;                        // (B,L,DIM1)
    float* alpha = label + (size_t)B_ * L_ * DIM1;       // (B,L,P)

    hipLaunchKernelGGL(cvt_bf16_kernel, dim3(2048), dim3(256), 0, stream,
                       x1, x1b, (B_ * P_ * DIM1) / 4);
    hipLaunchKernelGGL(cvt_bf16_kernel, dim3(512), dim3(256), 0, stream,
                       W1, W1b, (ATT * DIM1) / 4);
    hipLaunchKernelGGL(weff_kernel, dim3(8), dim3(256), 0, stream, Wh, Wt, w_eff);
    hipLaunchKernelGGL(gemm_nt, dim3((B_ * L_) / 64, ATT / 64), dim3(256), 0, stream,
                       x2, W2, p2, B_ * L_, ATT, DIM2);
    hipLaunchKernelGGL(gemm_bf16_mfma, dim3(GM / 64, GN / 64), dim3(256), 0, stream,
                       x1b, W1b, p1);
    hipLaunchKernelGGL(score_softmax_kernel, dim3(B_ * L_), dim3(256), 0, stream,
                       p1, p2, w_eff, alpha);
    hipLaunchKernelGGL(label_kernel, dim3(B_, 2, DIM1 / 256), dim3(256), 0, stream,
                       alpha, x1, label);
}

// Round 6
// 204.144 us; speedup vs baseline: 1.8627x; 1.2599x over previous
//
#include <hip/hip_runtime.h>

#define B_   16
#define P_   196
#define L_   80
#define DIM1 2048
#define DIM2 300
#define ATT  512

typedef __attribute__((ext_vector_type(8))) short short8x;
typedef __attribute__((ext_vector_type(4))) float f32x4;
typedef __attribute__((ext_vector_type(4))) unsigned int uint4x;
typedef __attribute__((ext_vector_type(4))) unsigned short ushort4x;

// ---------------- w_eff[a] = sum_c Wt[c] * Wh[c,a] ----------------
__global__ __launch_bounds__(256)
void weff_kernel(const float* __restrict__ Wh, const float* __restrict__ Wt,
                 float* __restrict__ w_eff) {
    __shared__ float part[4][64];
    const int tid = threadIdx.x, lane = tid & 63, quad = tid >> 6;
    const int a = blockIdx.x * 64 + lane;
    float s = 0.f;
    const int c0 = quad * 128;
    for (int c = c0; c < c0 + 128; ++c)
        s = fmaf(Wt[c], Wh[(size_t)c * ATT + a], s);
    part[quad][lane] = s;
    __syncthreads();
    if (tid < 64)
        w_eff[blockIdx.x * 64 + tid] =
            (part[0][tid] + part[1][tid]) + (part[2][tid] + part[3][tid]);
}

// ---------------- fp32 -> bf16 (RN-even), vectorized x4 ----------------
__global__ __launch_bounds__(256)
void cvt_bf16_kernel(const float* __restrict__ in, unsigned short* __restrict__ out, int n4) {
    for (int i = blockIdx.x * 256 + threadIdx.x; i < n4; i += gridDim.x * 256) {
        uint4x u = ((const uint4x*)in)[i];
        ushort4x o;
        #pragma unroll
        for (int j = 0; j < 4; ++j) {
            unsigned v = u[j];
            v += 0x7fffu + ((v >> 16) & 1u);
            o[j] = (unsigned short)(v >> 16);
        }
        ((ushort4x*)out)[i] = o;
    }
}

// ---------------- bf16 MFMA GEMM: C[M,N] = A[M,K] * B[N,K]^T ----------------
#define GM 3136
#define GN 512
#define GK 2048

__device__ __forceinline__ void gload16(const unsigned short* g, unsigned short* l) {
    __builtin_amdgcn_global_load_lds(
        (const __attribute__((address_space(1))) unsigned int*)g,
        (__attribute__((address_space(3))) unsigned int*)l, 16, 0, 0);
}

__global__ __launch_bounds__(256)
void gemm_bf16_mfma(const unsigned short* __restrict__ Ab,
                    const unsigned short* __restrict__ Bb,
                    float* __restrict__ C) {
    __shared__ unsigned short As[2][64 * 64];
    __shared__ unsigned short Bs[2][64 * 64];
    const int tid  = threadIdx.x;
    const int wid  = tid >> 6;
    const int lane = tid & 63;
    const int bm   = blockIdx.x * 64;
    const int bn   = blockIdx.y * 64;
    const int wm   = wid >> 1;          // 0,1
    const int wn   = wid & 1;           // 0,1

    const int srow = lane >> 3;                       // 0..7
    const int scol = ((lane & 7) ^ srow) << 3;        // pre-swizzled source col
    const size_t arow0 = (size_t)(bm + (wid << 4) + srow) * GK;
    const size_t brow0 = (size_t)(bn + (wid << 4) + srow) * GK;

#define STAGE_TILE(buf, k0)                                                        \
    {                                                                              \
        gload16(Ab + arow0 + (k0) + scol,            &As[buf][((wid << 4) + 0) * 64]); \
        gload16(Ab + arow0 + (size_t)8 * GK + (k0) + scol, &As[buf][((wid << 4) + 8) * 64]); \
        gload16(Bb + brow0 + (k0) + scol,            &Bs[buf][((wid << 4) + 0) * 64]); \
        gload16(Bb + brow0 + (size_t)8 * GK + (k0) + scol, &Bs[buf][((wid << 4) + 8) * 64]); \
    }

    f32x4 acc[2][2] = {};
    const int fr  = lane & 15;
    const int kb  = (lane >> 4) << 3;
    const int swz = (lane & 7) << 4;

    STAGE_TILE(0, 0)
    constexpr int NT = GK / 64;
    for (int kt = 0; kt < NT; ++kt) {
        __syncthreads();
        if (kt + 1 < NT) STAGE_TILE((kt + 1) & 1, (kt + 1) * 64)
        const char* pa = (const char*)&As[kt & 1][0];
        const char* pb = (const char*)&Bs[kt & 1][0];
        #pragma unroll
        for (int kk = 0; kk < 2; ++kk) {
            const int koff = ((kk * 32 + kb) * 2) ^ swz;
            short8x a[2], b[2];
            #pragma unroll
            for (int m = 0; m < 2; ++m)
                a[m] = *(const short8x*)(pa + (wm * 32 + m * 16 + fr) * 128 + koff);
            #pragma unroll
            for (int n = 0; n < 2; ++n)
                b[n] = *(const short8x*)(pb + (wn * 32 + n * 16 + fr) * 128 + koff);
            #pragma unroll
            for (int m = 0; m < 2; ++m)
                #pragma unroll
                for (int n = 0; n < 2; ++n)
                    acc[m][n] = __builtin_amdgcn_mfma_f32_16x16x32_bf16(a[m], b[n], acc[m][n], 0, 0, 0);
        }
        __syncthreads();
    }

    const int crow = (lane >> 4) << 2;
    #pragma unroll
    for (int m = 0; m < 2; ++m)
        #pragma unroll
        for (int n = 0; n < 2; ++n)
            #pragma unroll
            for (int j = 0; j < 4; ++j)
                C[(size_t)(bm + wm * 32 + m * 16 + crow + j) * GN + bn + wn * 32 + n * 16 + fr] =
                    acc[m][n][j];
#undef STAGE_TILE
}

// ---------- generic tiled NT GEMM (fp32): C[M,N] = A[M,K] * B[N,K]^T ----------
__global__ __launch_bounds__(256)
void gemm_nt(const float* __restrict__ A, const float* __restrict__ Bm,
             float* __restrict__ C, int M, int N, int K) {
    constexpr int BK = 16;
    __shared__ float As[BK][64];
    __shared__ float Bs[BK][64];
    const int tid  = threadIdx.x;
    const int bm   = blockIdx.x * 64;
    const int bn   = blockIdx.y * 64;
    const int ty   = tid >> 4;
    const int tx   = tid & 15;
    const int lrow = tid >> 2;
    const int lc4  = (tid & 3) << 2;
    float acc[4][4] = {};
    const float* Arow = A  + (size_t)(bm + lrow) * K;
    const float* Brow = Bm + (size_t)(bn + lrow) * K;

    for (int k0 = 0; k0 < K; k0 += BK) {
        float4 av, bv;
        if (k0 + BK <= K) {
            av = *(const float4*)(Arow + k0 + lc4);
            bv = *(const float4*)(Brow + k0 + lc4);
        } else {
            float a_[4], b_[4];
            #pragma unroll
            for (int i = 0; i < 4; ++i) {
                const int k = k0 + lc4 + i;
                a_[i] = (k < K) ? Arow[k] : 0.f;
                b_[i] = (k < K) ? Brow[k] : 0.f;
            }
            av = make_float4(a_[0], a_[1], a_[2], a_[3]);
            bv = make_float4(b_[0], b_[1], b_[2], b_[3]);
        }
        __syncthreads();
        As[lc4 + 0][lrow] = av.x;
        As[lc4 + 1][lrow] = av.y;
        As[lc4 + 2][lrow] = av.z;
        As[lc4 + 3][lrow] = av.w;
        Bs[lc4 + 0][lrow] = bv.x;
        Bs[lc4 + 1][lrow] = bv.y;
        Bs[lc4 + 2][lrow] = bv.z;
        Bs[lc4 + 3][lrow] = bv.w;
        __syncthreads();
        #pragma unroll
        for (int k = 0; k < BK; ++k) {
            const float4 a4 = *(const float4*)&As[k][ty << 2];
            const float4 b4 = *(const float4*)&Bs[k][tx << 2];
            const float ae[4] = {a4.x, a4.y, a4.z, a4.w};
            const float be[4] = {b4.x, b4.y, b4.z, b4.w};
            #pragma unroll
            for (int i = 0; i < 4; ++i)
                #pragma unroll
                for (int j = 0; j < 4; ++j)
                    acc[i][j] = fmaf(ae[i], be[j], acc[i][j]);
        }
    }
    #pragma unroll
    for (int i = 0; i < 4; ++i) {
        float4 o = make_float4(acc[i][0], acc[i][1], acc[i][2], acc[i][3]);
        *(float4*)(C + (size_t)(bm + (ty << 2) + i) * N + bn + (tx << 2)) = o;
    }
}

// ------- fused score + softmax: one block per (b,l); writes alpha -------
#define LOG2E2 2.8853900817779268f   // 2*log2(e)

__global__ __launch_bounds__(256)
void score_softmax_kernel(const float* __restrict__ p1, const float* __restrict__ p2,
                          const float* __restrict__ w_eff, float* __restrict__ alpha) {
    // XCD-chunked swizzle: 1280 blocks = 8 XCDs x 160 -> same-b blocks share L2
    const int bidx = blockIdx.x;
    const int bl = (bidx & 7) * 160 + (bidx >> 3);
    const int b  = bl / L_;
    __shared__ float s_t[P_];
    __shared__ float s_red[4];
    const int tid = threadIdx.x, wave = tid >> 6, lane = tid & 63;

    const float4* gp2 = (const float4*)(p2 + (size_t)bl * ATT);
    const float4* gw  = (const float4*)w_eff;
    const float4 q0 = gp2[lane], q1 = gp2[64 + lane];
    const float4 w0 = gw[lane],  w1 = gw[64 + lane];
    float qa[8] = {q0.x * LOG2E2, q0.y * LOG2E2, q0.z * LOG2E2, q0.w * LOG2E2,
                   q1.x * LOG2E2, q1.y * LOG2E2, q1.z * LOG2E2, q1.w * LOG2E2};
    float wa[8] = {w0.x, w0.y, w0.z, w0.w, w1.x, w1.y, w1.z, w1.w};

    const float* p1b = p1 + (size_t)b * P_ * ATT;
    for (int p = wave; p < P_; p += 4) {
        const float4* row = (const float4*)(p1b + (size_t)p * ATT);
        const float4 r0 = row[lane], r1 = row[64 + lane];
        const float rr[8] = {r0.x, r0.y, r0.z, r0.w, r1.x, r1.y, r1.z, r1.w};
        float acc = 0.f;
        #pragma unroll
        for (int j = 0; j < 8; ++j) {
            const float e = __builtin_amdgcn_exp2f(rr[j] * qa[j]);
            acc = fmaf(wa[j], __builtin_amdgcn_rcpf(e + 1.f), acc);
        }
        #pragma unroll
        for (int off = 32; off >= 1; off >>= 1) acc += __shfl_xor(acc, off);
        if (lane == 0) s_t[p] = acc;
    }
    __syncthreads();
    const float v = (tid < P_) ? -2.f * s_t[tid] : -1e30f;
    float m = v;
    #pragma unroll
    for (int off = 32; off >= 1; off >>= 1) m = fmaxf(m, __shfl_xor(m, off));
    if (lane == 0) s_red[wave] = m;
    __syncthreads();
    m = fmaxf(fmaxf(s_red[0], s_red[1]), fmaxf(s_red[2], s_red[3]));
    __syncthreads();
    const float e = (tid < P_) ? __expf(v - m) : 0.f;
    float s = e;
    #pragma unroll
    for (int off = 32; off >= 1; off >>= 1) s += __shfl_xor(s, off);
    if (lane == 0) s_red[wave] = s;
    __syncthreads();
    s = s_red[0] + s_red[1] + s_red[2] + s_red[3];
    if (tid < P_) alpha[(size_t)bl * P_ + tid] = e / s;
}

// ------- label_repr[b,l,d] = sum_p alpha[b,l,p] * x1[b,p,d] -------
// grid (8 dt, 5 lt, 16 b) = 640 blocks; 16 l's/block; alpha in LDS as [p][16]
// (float4 broadcast reads); p-loop unrolled x4 with explicit load batch.
__global__ __launch_bounds__(256)
void label_kernel(const float* __restrict__ alpha, const float* __restrict__ x1,
                  float* __restrict__ out) {
    const int dt = blockIdx.x;   // 0..7
    const int lt = blockIdx.y;   // 0..4
    const int b  = blockIdx.z;   // 0..15
    __shared__ float s_alpha[P_][16];
    const int tid = threadIdx.x;
    for (int idx = tid; idx < 16 * P_; idx += 256) {
        const int p = idx >> 4, i = idx & 15;
        s_alpha[p][i] = alpha[(size_t)(b * L_ + lt * 16 + i) * P_ + p];
    }
    __syncthreads();
    const int d = dt * 256 + tid;
    const float* xcol = x1 + (size_t)b * P_ * DIM1 + d;
    float acc[16] = {};
    for (int p = 0; p < P_; p += 4) {            // 196 = 4*49, no tail
        float xv[4];
        #pragma unroll
        for (int u = 0; u < 4; ++u) xv[u] = xcol[(size_t)(p + u) * DIM1];
        #pragma unroll
        for (int u = 0; u < 4; ++u) {
            const float4 a0 = *(const float4*)&s_alpha[p + u][0];
            const float4 a1 = *(const float4*)&s_alpha[p + u][4];
            const float4 a2 = *(const float4*)&s_alpha[p + u][8];
            const float4 a3 = *(const float4*)&s_alpha[p + u][12];
            acc[0]  = fmaf(a0.x, xv[u], acc[0]);
            acc[1]  = fmaf(a0.y, xv[u], acc[1]);
            acc[2]  = fmaf(a0.z, xv[u], acc[2]);
            acc[3]  = fmaf(a0.w, xv[u], acc[3]);
            acc[4]  = fmaf(a1.x, xv[u], acc[4]);
            acc[5]  = fmaf(a1.y, xv[u], acc[5]);
            acc[6]  = fmaf(a1.z, xv[u], acc[6]);
            acc[7]  = fmaf(a1.w, xv[u], acc[7]);
            acc[8]  = fmaf(a2.x, xv[u], acc[8]);
            acc[9]  = fmaf(a2.y, xv[u], acc[9]);
            acc[10] = fmaf(a2.z, xv[u], acc[10]);
            acc[11] = fmaf(a2.w, xv[u], acc[11]);
            acc[12] = fmaf(a3.x, xv[u], acc[12]);
            acc[13] = fmaf(a3.y, xv[u], acc[13]);
            acc[14] = fmaf(a3.z, xv[u], acc[14]);
            acc[15] = fmaf(a3.w, xv[u], acc[15]);
        }
    }
    #pragma unroll
    for (int i = 0; i < 16; ++i)
        out[(size_t)(b * L_ + lt * 16 + i) * DIM1 + d] = acc[i];
}

extern "C" void kernel_launch(void* const* d_in, const int* in_sizes, int n_in,
                              void* d_out, int out_size, void* d_ws, size_t ws_size,
                              hipStream_t stream) {
    const float* x1 = (const float*)d_in[0];   // (B,P,DIM1)
    const float* x2 = (const float*)d_in[1];   // (B,L,DIM2)
    const float* W1 = (const float*)d_in[2];   // (ATT,DIM1)
    const float* W2 = (const float*)d_in[3];   // (ATT,DIM2)
    const float* Wh = (const float*)d_in[4];   // (ATT,ATT)
    const float* Wt = (const float*)d_in[6];   // (1,ATT)
    // bh (d_in[5]) and bt (d_in[7]) cancel in the softmax — unused.

    float* ws    = (float*)d_ws;
    float* p1    = ws;                                   // 3136*512 f32
    float* p2    = p1 + (size_t)B_ * P_ * ATT;           // 1280*512 f32
    float* w_eff = p2 + (size_t)B_ * L_ * ATT;           // 512 f32
    unsigned short* x1b = (unsigned short*)(w_eff + ATT);        // 3136*2048 bf16
    unsigned short* W1b = x1b + (size_t)B_ * P_ * DIM1;          // 512*2048 bf16

    float* label = (float*)d_out;                        // (B,L,DIM1)
    float* alpha = label + (size_t)B_ * L_ * DIM1;       // (B,L,P)

    hipLaunchKernelGGL(cvt_bf16_kernel, dim3(2048), dim3(256), 0, stream,
                       x1, x1b, (B_ * P_ * DIM1) / 4);
    hipLaunchKernelGGL(cvt_bf16_kernel, dim3(512), dim3(256), 0, stream,
                       W1, W1b, (ATT * DIM1) / 4);
    hipLaunchKernelGGL(weff_kernel, dim3(8), dim3(256), 0, stream, Wh, Wt, w_eff);
    hipLaunchKernelGGL(gemm_nt, dim3((B_ * L_) / 64, ATT / 64), dim3(256), 0, stream,
                       x2, W2, p2, B_ * L_, ATT, DIM2);
    hipLaunchKernelGGL(gemm_bf16_mfma, dim3(GM / 64, GN / 64), dim3(256), 0, stream,
                       x1b, W1b, p1);
    hipLaunchKernelGGL(score_softmax_kernel, dim3(B_ * L_), dim3(256), 0, stream,
                       p1, p2, w_eff, alpha);
    hipLaunchKernelGGL(label_kernel, dim3(8, 5, B_), dim3(256), 0, stream,
                       alpha, x1, label);
}

// Round 7
// 196.915 us; speedup vs baseline: 1.9311x; 1.0367x over previous
//
#include <hip/hip_runtime.h>

#define B_   16
#define P_   196
#define L_   80
#define DIM1 2048
#define DIM2 300
#define ATT  512

typedef __attribute__((ext_vector_type(8))) short short8x;
typedef __attribute__((ext_vector_type(4))) float f32x4;
typedef __attribute__((ext_vector_type(4))) unsigned int uint4x;
typedef __attribute__((ext_vector_type(4))) unsigned short ushort4x;

// ---------------- w_eff[a] = sum_c Wt[c] * Wh[c,a] ----------------
__global__ __launch_bounds__(256)
void weff_kernel(const float* __restrict__ Wh, const float* __restrict__ Wt,
                 float* __restrict__ w_eff) {
    __shared__ float part[4][64];
    const int tid = threadIdx.x, lane = tid & 63, quad = tid >> 6;
    const int a = blockIdx.x * 64 + lane;
    float s = 0.f;
    const int c0 = quad * 128;
    for (int c = c0; c < c0 + 128; ++c)
        s = fmaf(Wt[c], Wh[(size_t)c * ATT + a], s);
    part[quad][lane] = s;
    __syncthreads();
    if (tid < 64)
        w_eff[blockIdx.x * 64 + tid] =
            (part[0][tid] + part[1][tid]) + (part[2][tid] + part[3][tid]);
}

// ---------------- fp32 -> bf16 (RN-even), vectorized x4 ----------------
__global__ __launch_bounds__(256)
void cvt_bf16_kernel(const float* __restrict__ in, unsigned short* __restrict__ out, int n4) {
    for (int i = blockIdx.x * 256 + threadIdx.x; i < n4; i += gridDim.x * 256) {
        uint4x u = ((const uint4x*)in)[i];
        ushort4x o;
        #pragma unroll
        for (int j = 0; j < 4; ++j) {
            unsigned v = u[j];
            v += 0x7fffu + ((v >> 16) & 1u);
            o[j] = (unsigned short)(v >> 16);
        }
        ((ushort4x*)out)[i] = o;
    }
}

// ---------------- bf16 MFMA GEMM: C[M,N] = A[M,K] * B[N,K]^T ----------------
// 64x32 tile (BK=64), 4 waves stacked along M (16 rows each, all 32 cols).
// grid (M/64, N/32) = (49,16) = 784 blocks (~3/CU). Both-sides XOR swizzle.
#define GM 3136
#define GN 512
#define GK 2048

__device__ __forceinline__ void gload16(const unsigned short* g, unsigned short* l) {
    __builtin_amdgcn_global_load_lds(
        (const __attribute__((address_space(1))) unsigned int*)g,
        (__attribute__((address_space(3))) unsigned int*)l, 16, 0, 0);
}

__global__ __launch_bounds__(256)
void gemm_bf16_mfma(const unsigned short* __restrict__ Ab,
                    const unsigned short* __restrict__ Bb,
                    float* __restrict__ C) {
    __shared__ unsigned short As[2][64 * 64];
    __shared__ unsigned short Bs[2][32 * 64];
    const int tid  = threadIdx.x;
    const int wid  = tid >> 6;
    const int lane = tid & 63;
    const int bm   = blockIdx.x * 64;
    const int bn   = blockIdx.y * 32;

    const int srow = lane >> 3;                       // 0..7
    const int scol = ((lane & 7) ^ srow) << 3;        // pre-swizzled source col
    const size_t arow0 = (size_t)(bm + (wid << 4) + srow) * GK;
    const size_t brow0 = (size_t)(bn + (wid << 3) + srow) * GK;

#define STAGE_TILE(buf, k0)                                                              \
    {                                                                                    \
        gload16(Ab + arow0 + (k0) + scol,                  &As[buf][((wid << 4) + 0) * 64]); \
        gload16(Ab + arow0 + (size_t)8 * GK + (k0) + scol, &As[buf][((wid << 4) + 8) * 64]); \
        gload16(Bb + brow0 + (k0) + scol,                  &Bs[buf][(wid << 3) * 64]);       \
    }

    f32x4 acc[2] = {};
    const int fr  = lane & 15;
    const int kb  = (lane >> 4) << 3;
    const int swz = (lane & 7) << 4;

    STAGE_TILE(0, 0)
    constexpr int NT = GK / 64;
    for (int kt = 0; kt < NT; ++kt) {
        __syncthreads();
        if (kt + 1 < NT) STAGE_TILE((kt + 1) & 1, (kt + 1) * 64)
        const char* pa = (const char*)&As[kt & 1][0];
        const char* pb = (const char*)&Bs[kt & 1][0];
        #pragma unroll
        for (int kk = 0; kk < 2; ++kk) {
            const int koff = ((kk * 32 + kb) * 2) ^ swz;
            short8x a = *(const short8x*)(pa + ((wid << 4) + fr) * 128 + koff);
            short8x b[2];
            #pragma unroll
            for (int n = 0; n < 2; ++n)
                b[n] = *(const short8x*)(pb + (n * 16 + fr) * 128 + koff);
            #pragma unroll
            for (int n = 0; n < 2; ++n)
                acc[n] = __builtin_amdgcn_mfma_f32_16x16x32_bf16(a, b[n], acc[n], 0, 0, 0);
        }
        __syncthreads();
    }

    const int crow = (lane >> 4) << 2;
    #pragma unroll
    for (int n = 0; n < 2; ++n)
        #pragma unroll
        for (int j = 0; j < 4; ++j)
            C[(size_t)(bm + (wid << 4) + crow + j) * GN + bn + n * 16 + fr] = acc[n][j];
#undef STAGE_TILE
}

// ---------- generic tiled NT GEMM (fp32): C[M,N] = A[M,K] * B[N,K]^T ----------
__global__ __launch_bounds__(256)
void gemm_nt(const float* __restrict__ A, const float* __restrict__ Bm,
             float* __restrict__ C, int M, int N, int K) {
    constexpr int BK = 16;
    __shared__ float As[BK][64];
    __shared__ float Bs[BK][64];
    const int tid  = threadIdx.x;
    const int bm   = blockIdx.x * 64;
    const int bn   = blockIdx.y * 64;
    const int ty   = tid >> 4;
    const int tx   = tid & 15;
    const int lrow = tid >> 2;
    const int lc4  = (tid & 3) << 2;
    float acc[4][4] = {};
    const float* Arow = A  + (size_t)(bm + lrow) * K;
    const float* Brow = Bm + (size_t)(bn + lrow) * K;

    for (int k0 = 0; k0 < K; k0 += BK) {
        float4 av, bv;
        if (k0 + BK <= K) {
            av = *(const float4*)(Arow + k0 + lc4);
            bv = *(const float4*)(Brow + k0 + lc4);
        } else {
            float a_[4], b_[4];
            #pragma unroll
            for (int i = 0; i < 4; ++i) {
                const int k = k0 + lc4 + i;
                a_[i] = (k < K) ? Arow[k] : 0.f;
                b_[i] = (k < K) ? Brow[k] : 0.f;
            }
            av = make_float4(a_[0], a_[1], a_[2], a_[3]);
            bv = make_float4(b_[0], b_[1], b_[2], b_[3]);
        }
        __syncthreads();
        As[lc4 + 0][lrow] = av.x;
        As[lc4 + 1][lrow] = av.y;
        As[lc4 + 2][lrow] = av.z;
        As[lc4 + 3][lrow] = av.w;
        Bs[lc4 + 0][lrow] = bv.x;
        Bs[lc4 + 1][lrow] = bv.y;
        Bs[lc4 + 2][lrow] = bv.z;
        Bs[lc4 + 3][lrow] = bv.w;
        __syncthreads();
        #pragma unroll
        for (int k = 0; k < BK; ++k) {
            const float4 a4 = *(const float4*)&As[k][ty << 2];
            const float4 b4 = *(const float4*)&Bs[k][tx << 2];
            const float ae[4] = {a4.x, a4.y, a4.z, a4.w};
            const float be[4] = {b4.x, b4.y, b4.z, b4.w};
            #pragma unroll
            for (int i = 0; i < 4; ++i)
                #pragma unroll
                for (int j = 0; j < 4; ++j)
                    acc[i][j] = fmaf(ae[i], be[j], acc[i][j]);
        }
    }
    #pragma unroll
    for (int i = 0; i < 4; ++i) {
        float4 o = make_float4(acc[i][0], acc[i][1], acc[i][2], acc[i][3]);
        *(float4*)(C + (size_t)(bm + (ty << 2) + i) * N + bn + (tx << 2)) = o;
    }
}

// ------- fused score + softmax: one block per (b,l); writes alpha -------
// v2: 16-lane row-groups (4 rows/wave-pass), double-buffered loads,
// pair-rcp: w1*sig1+w2*sig2 = (w1*e2+w2*e1+w1+w2) / ((1+e1)(1+e2)).
#define LOG2E2 2.8853900817779268f   // 2*log2(e)

__global__ __launch_bounds__(256)
void score_softmax_kernel(const float* __restrict__ p1, const float* __restrict__ p2,
                          const float* __restrict__ w_eff, float* __restrict__ alpha) {
    // XCD-chunked swizzle: 1280 blocks = 8 XCDs x 160 -> same-b blocks share L2
    const int bidx = blockIdx.x;
    const int bl = (bidx & 7) * 160 + (bidx >> 3);
    const int b  = bl / L_;
    __shared__ float s_t[P_];
    __shared__ float s_red[4];
    const int tid = threadIdx.x, wave = tid >> 6, lane = tid & 63;
    const int g = lane >> 4, c = lane & 15;   // row-group, lane-in-group

    // per-lane a-slots: float4 index c + 16j (j=0..7) -> coalesced per group
    const float4* gp2 = (const float4*)(p2 + (size_t)bl * ATT);
    const float4* gw  = (const float4*)w_eff;
    float4 qa[8], wa[8];
    #pragma unroll
    for (int j = 0; j < 8; ++j) {
        const float4 q = gp2[c + 16 * j];
        qa[j] = make_float4(q.x * LOG2E2, q.y * LOG2E2, q.z * LOG2E2, q.w * LOG2E2);
        wa[j] = gw[c + 16 * j];
    }

    const float* p1b = p1 + (size_t)b * P_ * ATT;
    // chunks: i in [0,12) -> rows 16i + 4*wave + g; tail chunk 12 (rows 192..195)
    // handled by wave 0 only.
    const int nch = (wave == 0) ? 13 : 12;
    int p = 16 * 0 + 4 * wave + g;
    int ptail = 192 + g;
    int row0 = (0 < 12) ? p : ptail;
    float4 cur[8], nxt[8];
    {
        const float4* row = (const float4*)(p1b + (size_t)row0 * ATT);
        #pragma unroll
        for (int j = 0; j < 8; ++j) cur[j] = row[c + 16 * j];
    }
    for (int i = 0; i < nch; ++i) {
        const int pr = (i < 12) ? (16 * i + 4 * wave + g) : ptail;
        if (i + 1 < nch) {
            const int pn = (i + 1 < 12) ? (16 * (i + 1) + 4 * wave + g) : ptail;
            const float4* row = (const float4*)(p1b + (size_t)pn * ATT);
            #pragma unroll
            for (int j = 0; j < 8; ++j) nxt[j] = row[c + 16 * j];
        }
        float acc = 0.f;
        #pragma unroll
        for (int j = 0; j < 8; ++j) {
            const float e0 = __builtin_amdgcn_exp2f(cur[j].x * qa[j].x);
            const float e1 = __builtin_amdgcn_exp2f(cur[j].y * qa[j].y);
            const float e2 = __builtin_amdgcn_exp2f(cur[j].z * qa[j].z);
            const float e3 = __builtin_amdgcn_exp2f(cur[j].w * qa[j].w);
            // pair (x,y)
            float num = fmaf(wa[j].x, e1, fmaf(wa[j].y, e0, wa[j].x + wa[j].y));
            float den = fmaf(e0, e1, e0 + e1 + 1.f);
            acc = fmaf(num, __builtin_amdgcn_rcpf(den), acc);
            // pair (z,w)
            num = fmaf(wa[j].z, e3, fmaf(wa[j].w, e2, wa[j].z + wa[j].w));
            den = fmaf(e2, e3, e2 + e3 + 1.f);
            acc = fmaf(num, __builtin_amdgcn_rcpf(den), acc);
        }
        // reduce across the 16 lanes of this row-group (4 rows at once)
        acc += __shfl_xor(acc, 1);
        acc += __shfl_xor(acc, 2);
        acc += __shfl_xor(acc, 4);
        acc += __shfl_xor(acc, 8);
        if (c == 0) s_t[pr] = acc;
        #pragma unroll
        for (int j = 0; j < 8; ++j) cur[j] = nxt[j];
    }
    __syncthreads();
    // softmax over p of v = -2*S   (TAU = 1; bias & Wsum cancel)
    const float v = (tid < P_) ? -2.f * s_t[tid] : -1e30f;
    float m = v;
    #pragma unroll
    for (int off = 32; off >= 1; off >>= 1) m = fmaxf(m, __shfl_xor(m, off));
    if (lane == 0) s_red[wave] = m;
    __syncthreads();
    m = fmaxf(fmaxf(s_red[0], s_red[1]), fmaxf(s_red[2], s_red[3]));
    __syncthreads();
    const float e = (tid < P_) ? __expf(v - m) : 0.f;
    float s = e;
    #pragma unroll
    for (int off = 32; off >= 1; off >>= 1) s += __shfl_xor(s, off);
    if (lane == 0) s_red[wave] = s;
    __syncthreads();
    s = s_red[0] + s_red[1] + s_red[2] + s_red[3];
    if (tid < P_) alpha[(size_t)bl * P_ + tid] = e / s;
}

// ------- label_repr[b,l,d] = sum_p alpha[b,l,p] * x1[b,p,d] -------
__global__ __launch_bounds__(256)
void label_kernel(const float* __restrict__ alpha, const float* __restrict__ x1,
                  float* __restrict__ out) {
    const int dt = blockIdx.x;   // 0..7
    const int lt = blockIdx.y;   // 0..4
    const int b  = blockIdx.z;   // 0..15
    __shared__ float s_alpha[P_][16];
    const int tid = threadIdx.x;
    for (int idx = tid; idx < 16 * P_; idx += 256) {
        const int p = idx >> 4, i = idx & 15;
        s_alpha[p][i] = alpha[(size_t)(b * L_ + lt * 16 + i) * P_ + p];
    }
    __syncthreads();
    const int d = dt * 256 + tid;
    const float* xcol = x1 + (size_t)b * P_ * DIM1 + d;
    float acc[16] = {};
    for (int p = 0; p < P_; p += 4) {            // 196 = 4*49, no tail
        float xv[4];
        #pragma unroll
        for (int u = 0; u < 4; ++u) xv[u] = xcol[(size_t)(p + u) * DIM1];
        #pragma unroll
        for (int u = 0; u < 4; ++u) {
            const float4 a0 = *(const float4*)&s_alpha[p + u][0];
            const float4 a1 = *(const float4*)&s_alpha[p + u][4];
            const float4 a2 = *(const float4*)&s_alpha[p + u][8];
            const float4 a3 = *(const float4*)&s_alpha[p + u][12];
            acc[0]  = fmaf(a0.x, xv[u], acc[0]);
            acc[1]  = fmaf(a0.y, xv[u], acc[1]);
            acc[2]  = fmaf(a0.z, xv[u], acc[2]);
            acc[3]  = fmaf(a0.w, xv[u], acc[3]);
            acc[4]  = fmaf(a1.x, xv[u], acc[4]);
            acc[5]  = fmaf(a1.y, xv[u], acc[5]);
            acc[6]  = fmaf(a1.z, xv[u], acc[6]);
            acc[7]  = fmaf(a1.w, xv[u], acc[7]);
            acc[8]  = fmaf(a2.x, xv[u], acc[8]);
            acc[9]  = fmaf(a2.y, xv[u], acc[9]);
            acc[10] = fmaf(a2.z, xv[u], acc[10]);
            acc[11] = fmaf(a2.w, xv[u], acc[11]);
            acc[12] = fmaf(a3.x, xv[u], acc[12]);
            acc[13] = fmaf(a3.y, xv[u], acc[13]);
            acc[14] = fmaf(a3.z, xv[u], acc[14]);
            acc[15] = fmaf(a3.w, xv[u], acc[15]);
        }
    }
    #pragma unroll
    for (int i = 0; i < 16; ++i)
        out[(size_t)(b * L_ + lt * 16 + i) * DIM1 + d] = acc[i];
}

extern "C" void kernel_launch(void* const* d_in, const int* in_sizes, int n_in,
                              void* d_out, int out_size, void* d_ws, size_t ws_size,
                              hipStream_t stream) {
    const float* x1 = (const float*)d_in[0];   // (B,P,DIM1)
    const float* x2 = (const float*)d_in[1];   // (B,L,DIM2)
    const float* W1 = (const float*)d_in[2];   // (ATT,DIM1)
    const float* W2 = (const float*)d_in[3];   // (ATT,DIM2)
    const float* Wh = (const float*)d_in[4];   // (ATT,ATT)
    const float* Wt = (const float*)d_in[6];   // (1,ATT)
    // bh (d_in[5]) and bt (d_in[7]) cancel in the softmax — unused.

    float* ws    = (float*)d_ws;
    float* p1    = ws;                                   // 3136*512 f32
    float* p2    = p1 + (size_t)B_ * P_ * ATT;           // 1280*512 f32
    float* w_eff = p2 + (size_t)B_ * L_ * ATT;           // 512 f32
    unsigned short* x1b = (unsigned short*)(w_eff + ATT);        // 3136*2048 bf16
    unsigned short* W1b = x1b + (size_t)B_ * P_ * DIM1;          // 512*2048 bf16

    float* label = (float*)d_out;                        // (B,L,DIM1)
    float* alpha = label + (size_t)B_ * L_ * DIM1;       // (B,L,P)

    hipLaunchKernelGGL(cvt_bf16_kernel, dim3(2048), dim3(256), 0, stream,
                       x1, x1b, (B_ * P_ * DIM1) / 4);
    hipLaunchKernelGGL(cvt_bf16_kernel, dim3(512), dim3(256), 0, stream,
                       W1, W1b, (ATT * DIM1) / 4);
    hipLaunchKernelGGL(weff_kernel, dim3(8), dim3(256), 0, stream, Wh, Wt, w_eff);
    hipLaunchKernelGGL(gemm_nt, dim3((B_ * L_) / 64, ATT / 64), dim3(256), 0, stream,
                       x2, W2, p2, B_ * L_, ATT, DIM2);
    hipLaunchKernelGGL(gemm_bf16_mfma, dim3(GM / 64, GN / 32), dim3(256), 0, stream,
                       x1b, W1b, p1);
    hipLaunchKernelGGL(score_softmax_kernel, dim3(B_ * L_), dim3(256), 0, stream,
                       p1, p2, w_eff, alpha);
    hipLaunchKernelGGL(label_kernel, dim3(8, 5, B_), dim3(256), 0, stream,
                       alpha, x1, label);
}